// Round 9
// baseline (2548.248 us; speedup 1.0000x reference)
//
#include <hip/hip_runtime.h>

typedef _Float16 half_t;
typedef _Float16 half8 __attribute__((ext_vector_type(8)));
typedef float f32x4 __attribute__((ext_vector_type(4)));
typedef unsigned long long u64;
typedef unsigned int u32;

#define GROUPS 16
#define WPG 8
#define NWG 128
#define THREADS 512
#define TSTEPS 512

// ws layout (halves / u32)
#define W0_HALVES (8*8*10*64*8)    // 327680
#define W1_HALVES (8*8*16*64*8)    // 524288
#define X_HALVES  (512*16*1024)    // 8388608
#define HX_HALVES (2*GROUPS*4096)  // per layer: 2 slots x 16 groups x (256h x 16b)
#define STAMP_U32 (2*GROUPS*64)    // per slot per group: 64 per-wave stamps (256B line)

__device__ __forceinline__ float sigm(float x){ return 1.f/(1.f+__expf(-x)); }
__device__ __forceinline__ float tanh_fast(float x){ float e=__expf(2.f*x); return 1.f - 2.f/(e+1.f); }

// W0 blocks: [jw 0..63][kc 0..9][lane][8]; wave jw=j*8+w owns h [jw*4, jw*4+4)
// tile row tr=lane&15: gate=tr&3, h_local=tr>>2 ; grow = gate*256 + jw*4 + h_local
// k = kc*32 + (lane>>4)*8 + jj ; K = [x(64) | h0(256)]
__global__ void prep_w0(const float* __restrict__ Wih, const float* __restrict__ Whh,
                        half_t* __restrict__ dst){
  int idx = blockIdx.x*blockDim.x + threadIdx.x;
  if (idx >= 8*8*10*64) return;
  int lane = idx & 63;
  int kc = (idx >> 6) % 10;
  int jw = idx / 640;
  int tr = lane & 15, kg = lane >> 4;
  int grow = (tr&3)*256 + jw*4 + (tr>>2);
  int k0 = kc*32 + kg*8;
  half_t* d = dst + (size_t)idx*8;
#pragma unroll
  for (int jj=0;jj<8;jj++){
    int k = k0 + jj;
    float v = (k < 64) ? Wih[grow*64 + k] : Whh[grow*256 + (k - 64)];
    d[jj] = (half_t)v;
  }
}

// W1 blocks: [jw][kc 0..15][lane][8]; K = [h0(256) | h1(256)]
__global__ void prep_w1(const float* __restrict__ Wih, const float* __restrict__ Whh,
                        half_t* __restrict__ dst){
  int idx = blockIdx.x*blockDim.x + threadIdx.x;
  if (idx >= 8*8*16*64) return;
  int lane = idx & 63;
  int kc = (idx >> 6) & 15;
  int jw = idx >> 10;
  int tr = lane & 15, kg = lane >> 4;
  int grow = (tr&3)*256 + jw*4 + (tr>>2);
  int k0 = kc*32 + kg*8;
  half_t* d = dst + (size_t)idx*8;
#pragma unroll
  for (int jj=0;jj<8;jj++){
    int k = k0 + jj;
    float v = (k < 256) ? Wih[grow*256 + k] : Whh[grow*256 + (k - 256)];
    d[jj] = (half_t)v;
  }
}

// x -> [t][g 0..15][k8 0..7][b 0..15][8] fp16 ; b_global = g*16+b, k = k8*8+jj
__global__ void prep_x(const float* __restrict__ x, half_t* __restrict__ xblk){
  int idx = blockIdx.x*blockDim.x + threadIdx.x;
  if (idx >= 512*16*8*16) return;
  int b = idx & 15;
  int k8 = (idx >> 4) & 7;
  int g = (idx >> 7) & 15;
  int t = idx >> 11;
  const float* src = x + ((size_t)(g*16+b)*512 + (size_t)t)*64 + k8*8;
  half_t* d = xblk + (size_t)idx*8;
#pragma unroll
  for (int jj=0;jj<8;jj++) d[jj] = (half_t)src[jj];
}

// persistent distributed 2-layer LSTM: 16 groups x 8 WGs; WG owns 32 h x 16 batch
// XCD-local groups: all 8 WGs of a group share bid%8 -> same XCD under round-robin
// fence-free exchange: relaxed sc1 stores -> s_waitcnt vmcnt(0) -> relaxed stamp
__global__ __launch_bounds__(THREADS, 2) void lstm_dist(
    const half_t* __restrict__ W0blk, const half_t* __restrict__ W1blk,
    const half_t* __restrict__ xblk,
    half_t* __restrict__ h0x, half_t* __restrict__ h1x, u32* __restrict__ stamps,
    const float* __restrict__ b_ih0, const float* __restrict__ b_hh0,
    const float* __restrict__ b_ih1, const float* __restrict__ b_hh1,
    const float* __restrict__ W_head, const float* __restrict__ b_head,
    float* __restrict__ out)
{
  __shared__ __align__(16) half_t hbuf[2][8192];  // [slot][h0:4096 | h1:4096] halves

  const int tid = threadIdx.x;
  const int wave = tid >> 6, lane = tid & 63;
  const int lcol = lane & 15, kg = lane >> 4;
  const int bid = blockIdx.x;
  // XCD-local group mapping: bids {k, k+8, .., k+56} + 64*h -> group k*2+h (all bid%8==k)
  const int g = ((bid & 7) << 1) | (bid >> 6);
  const int j = (bid >> 3) & 7;
  const int jw = j*8 + wave;

  // ---- one-time: A-fragments + biases into registers ----
  half8 a0[10], a1[16];
#pragma unroll
  for (int kc = 0; kc < 10; ++kc)
    a0[kc] = *(const half8*)(W0blk + ((size_t)(jw*10 + kc)*64 + lane)*8);
#pragma unroll
  for (int kc = 0; kc < 16; ++kc)
    a1[kc] = *(const half8*)(W1blk + ((size_t)(jw*16 + kc)*64 + lane)*8);
  // pin fragments (unified VGPR/AGPR file): prevent rematerialization in-loop
#pragma unroll
  for (int kc = 0; kc < 10; ++kc) asm volatile("" : "+v"(a0[kc]));
#pragma unroll
  for (int kc = 0; kc < 16; ++kc) asm volatile("" : "+v"(a1[kc]));

  const int hh = jw*4 + kg;     // this lane's hidden index (0..255)
  f32x4 bias0, bias1;
#pragma unroll
  for (int ri = 0; ri < 4; ++ri){
    bias0[ri] = b_ih0[ri*256+hh] + b_hh0[ri*256+hh];
    bias1[ri] = b_ih1[ri*256+hh] + b_hh1[ri*256+hh];
  }
  // even-kg lanes store packed u32 {hh, hh+1} at this u32 offset
  const int eoff_u32 = ((hh>>3)*128 + lcol*8 + (hh&7)) >> 1;

  float c0 = 0.f, c1 = 0.f;
  half8 xf0, xf1;
  {
    const half_t* xs = xblk + (size_t)g*1024;
    xf0 = *(const half8*)(xs + ((0*4+kg)*16 + lcol)*8);
    xf1 = *(const half8*)(xs + ((1*4+kg)*16 + lcol)*8);
  }

  for (int q = 0; q <= TSTEPS; ++q){
    const int sslot = (q+1)&1, dslot = q&1;

    // ---- poll per-wave stamps (relaxed only; 256B warm line, XCD-local) ----
    if (q > 0){
      const u32* sp = stamps + (size_t)(sslot*GROUPS + g)*64;
      const u32 want = (u32)q;
      int ok = 0;
      for (int tries = 0; !ok && tries < (1<<20); ++tries){
        u32 s = __hip_atomic_load(sp + lane, __ATOMIC_RELAXED, __HIP_MEMORY_SCOPE_AGENT);
        ok = __all((int)(s >= want));
      }
      __builtin_amdgcn_sched_barrier(0);   // keep payload loads below the poll
    }

    // ---- stage exchange slot -> LDS (1024 u64 per layer: 4 loads/thread) ----
    {
      const u64* s0 = (const u64*)(h0x + (size_t)(sslot*GROUPS + g)*4096);
      const u64* s1 = (const u64*)(h1x + (size_t)(sslot*GROUPS + g)*4096);
      u64* d = (u64*)hbuf[sslot];
      d[tid]        = __hip_atomic_load(s0 + tid,       __ATOMIC_RELAXED, __HIP_MEMORY_SCOPE_AGENT);
      d[tid + 512]  = __hip_atomic_load(s0 + tid + 512, __ATOMIC_RELAXED, __HIP_MEMORY_SCOPE_AGENT);
      d[tid + 1024] = __hip_atomic_load(s1 + tid,       __ATOMIC_RELAXED, __HIP_MEMORY_SCOPE_AGENT);
      d[tid + 1536] = __hip_atomic_load(s1 + tid + 512, __ATOMIC_RELAXED, __HIP_MEMORY_SCOPE_AGENT);
    }
    __syncthreads();

    const half_t* cb = hbuf[sslot];
    half8 h0f[8];
#pragma unroll
    for (int c = 0; c < 8; ++c)
      h0f[c] = *(const half8*)(cb + ((c*4+kg)*16 + lcol)*8);

    // ---- L0: step q ----
    if (q < TSTEPS){
      f32x4 acc = bias0;
      acc = __builtin_amdgcn_mfma_f32_16x16x32_f16(a0[0], xf0, acc, 0,0,0);
      acc = __builtin_amdgcn_mfma_f32_16x16x32_f16(a0[1], xf1, acc, 0,0,0);
#pragma unroll
      for (int c = 0; c < 8; ++c)
        acc = __builtin_amdgcn_mfma_f32_16x16x32_f16(a0[c+2], h0f[c], acc, 0,0,0);
      float ig=sigm(acc[0]), fg=sigm(acc[1]), gg=tanh_fast(acc[2]), og=sigm(acc[3]);
      c0 = fg*c0 + ig*gg;
      float hv = og*tanh_fast(c0);
      u32 mybits = (u32)__builtin_bit_cast(unsigned short, (half_t)hv);
      u32 other  = (u32)__shfl_xor((int)mybits, 16);
      if (!(kg & 1)){
        u32 pk = mybits | (other << 16);
        __hip_atomic_store((u32*)(h0x + (size_t)(dslot*GROUPS + g)*4096) + eoff_u32,
                           pk, __ATOMIC_RELAXED, __HIP_MEMORY_SCOPE_AGENT);
      }
    }

    // ---- L1: step q-1 ----
    if (q >= 1){
      f32x4 acc = bias1;
#pragma unroll
      for (int c = 0; c < 8; ++c)
        acc = __builtin_amdgcn_mfma_f32_16x16x32_f16(a1[c], h0f[c], acc, 0,0,0);
#pragma unroll
      for (int c = 0; c < 8; ++c){
        half8 h1f = *(const half8*)(cb + 4096 + ((c*4+kg)*16 + lcol)*8);
        acc = __builtin_amdgcn_mfma_f32_16x16x32_f16(a1[c+8], h1f, acc, 0,0,0);
      }
      float ig=sigm(acc[0]), fg=sigm(acc[1]), gg=tanh_fast(acc[2]), og=sigm(acc[3]);
      c1 = fg*c1 + ig*gg;
      float hv = og*tanh_fast(c1);
      u32 mybits = (u32)__builtin_bit_cast(unsigned short, (half_t)hv);
      u32 other  = (u32)__shfl_xor((int)mybits, 16);
      if (!(kg & 1)){
        u32 pk = mybits | (other << 16);
        __hip_atomic_store((u32*)(h1x + (size_t)(dslot*GROUPS + g)*4096) + eoff_u32,
                           pk, __ATOMIC_RELAXED, __HIP_MEMORY_SCOPE_AGENT);
      }
    }

    // ---- publish: drain this wave's payload stores (pure vmcnt drain, no
    // cache-maintenance), then relaxed stamp ----
    asm volatile("s_waitcnt vmcnt(0)" ::: "memory");
    if (lane == 0)
      __hip_atomic_store(stamps + (size_t)(dslot*GROUPS + g)*64 + jw, (u32)(q+1),
                         __ATOMIC_RELAXED, __HIP_MEMORY_SCOPE_AGENT);

    // ---- x prefetch for next phase (overlaps next poll) ----
    if (q+1 < TSTEPS){
      const half_t* xs = xblk + (size_t)((q+1)*16 + g)*1024;
      xf0 = *(const half8*)(xs + ((0*4+kg)*16 + lcol)*8);
      xf1 = *(const half8*)(xs + ((1*4+kg)*16 + lcol)*8);
    }
  }

  // ---- head: poll final h1(511) (slot0, stamp 513), stage, GEMV ----
  {
    const u32* sp = stamps + (size_t)(0*GROUPS + g)*64;
    const u32 want = (u32)(TSTEPS + 1);
    int ok = 0;
    for (int tries = 0; !ok && tries < (1<<20); ++tries){
      u32 s = __hip_atomic_load(sp + lane, __ATOMIC_RELAXED, __HIP_MEMORY_SCOPE_AGENT);
      ok = __all((int)(s >= want));
    }
    __builtin_amdgcn_sched_barrier(0);

    const u64* s1 = (const u64*)(h1x + (size_t)(0*GROUPS + g)*4096);
    u64* hd = (u64*)hbuf[0];
    hd[tid]       = __hip_atomic_load(s1 + tid,       __ATOMIC_RELAXED, __HIP_MEMORY_SCOPE_AGENT);
    hd[tid + 512] = __hip_atomic_load(s1 + tid + 512, __ATOMIC_RELAXED, __HIP_MEMORY_SCOPE_AGENT);
    __syncthreads();

    if (tid < 240){
      int bl = 2*j + (tid >= 120 ? 1 : 0);
      int o = tid % 120;
      float s2 = b_head[o];
      const float* wr = W_head + (size_t)o*256;
#pragma unroll 4
      for (int k8 = 0; k8 < 32; ++k8){
        half8 hv = *(const half8*)(hbuf[0] + (k8*16 + bl)*8);
#pragma unroll
        for (int jj = 0; jj < 8; ++jj)
          s2 += (float)hv[jj] * wr[k8*8 + jj];
      }
      out[((size_t)(g*16 + bl))*120 + o] = s2;
    }
  }
}

extern "C" void kernel_launch(void* const* d_in, const int* in_sizes, int n_in,
                              void* d_out, int out_size, void* d_ws, size_t ws_size,
                              hipStream_t stream){
  const float* x     = (const float*)d_in[0];
  const float* W_ih0 = (const float*)d_in[1];
  const float* W_hh0 = (const float*)d_in[2];
  const float* b_ih0 = (const float*)d_in[3];
  const float* b_hh0 = (const float*)d_in[4];
  const float* W_ih1 = (const float*)d_in[5];
  const float* W_hh1 = (const float*)d_in[6];
  const float* b_ih1 = (const float*)d_in[7];
  const float* b_hh1 = (const float*)d_in[8];
  const float* W_head= (const float*)d_in[9];
  const float* b_head= (const float*)d_in[10];
  float* out = (float*)d_out;

  half_t* W0blk = (half_t*)d_ws;
  half_t* W1blk = W0blk + W0_HALVES;
  half_t* xblk  = W1blk + W1_HALVES;
  half_t* h0x   = xblk + X_HALVES;
  half_t* h1x   = h0x + HX_HALVES;
  u32*    stamps= (u32*)(h1x + HX_HALVES);

  // zero exchange + stamps every launch (graph-replay safe; h0x/h1x/stamps contiguous)
  (void)hipMemsetAsync(h0x, 0, (size_t)HX_HALVES*2*2 + (size_t)STAMP_U32*4, stream);

  hipLaunchKernelGGL(prep_w0, dim3(160), dim3(256), 0, stream, W_ih0, W_hh0, W0blk);
  hipLaunchKernelGGL(prep_w1, dim3(256), dim3(256), 0, stream, W_ih1, W_hh1, W1blk);
  hipLaunchKernelGGL(prep_x,  dim3(4096), dim3(256), 0, stream, x, xblk);

  hipLaunchKernelGGL(lstm_dist, dim3(NWG), dim3(THREADS), 0, stream,
                     W0blk, W1blk, xblk, h0x, h1x, stamps,
                     b_ih0, b_hh0, b_ih1, b_hh1, W_head, b_head, out);
}

// Round 10
// 1542.211 us; speedup vs baseline: 1.6523x; 1.6523x over previous
//
#include <hip/hip_runtime.h>

typedef _Float16 half_t;
typedef _Float16 half8 __attribute__((ext_vector_type(8)));
typedef float f32x4 __attribute__((ext_vector_type(4)));
typedef unsigned long long u64;
typedef unsigned int u32;

#define GROUPS 16
#define WPG 8
#define NWG 128
#define THREADS 512
#define TSTEPS 512

// ws layout
#define W0_HALVES (8*8*10*64*8)    // 327680 halves
#define W1_HALVES (8*8*16*64*8)    // 524288 halves
#define X_HALVES  (512*16*1024)    // 8388608 halves
#define HX_U32    (2*GROUPS*4096)  // per layer: 2 slots x 16 groups x 4096 stamped u32

__device__ __forceinline__ float sigm(float x){ return 1.f/(1.f+__expf(-x)); }
__device__ __forceinline__ float tanh_fast(float x){ float e=__expf(2.f*x); return 1.f - 2.f/(e+1.f); }

// W0 blocks: [jw 0..63][kc 0..9][lane][8]; wave jw owns h [jw*4, jw*4+4)
// tile row tr=lane&15: gate=tr&3, h_local=tr>>2 ; grow = gate*256 + jw*4 + h_local
// k = kc*32 + (lane>>4)*8 + jj ; K = [x(64) | h0(256)]
__global__ void prep_w0(const float* __restrict__ Wih, const float* __restrict__ Whh,
                        half_t* __restrict__ dst){
  int idx = blockIdx.x*blockDim.x + threadIdx.x;
  if (idx >= 8*8*10*64) return;
  int lane = idx & 63;
  int kc = (idx >> 6) % 10;
  int jw = idx / 640;
  int tr = lane & 15, kg = lane >> 4;
  int grow = (tr&3)*256 + jw*4 + (tr>>2);
  int k0 = kc*32 + kg*8;
  half_t* d = dst + (size_t)idx*8;
#pragma unroll
  for (int jj=0;jj<8;jj++){
    int k = k0 + jj;
    float v = (k < 64) ? Wih[grow*64 + k] : Whh[grow*256 + (k - 64)];
    d[jj] = (half_t)v;
  }
}

// W1 blocks: [jw][kc 0..15][lane][8]; K = [h0(256) | h1(256)]
__global__ void prep_w1(const float* __restrict__ Wih, const float* __restrict__ Whh,
                        half_t* __restrict__ dst){
  int idx = blockIdx.x*blockDim.x + threadIdx.x;
  if (idx >= 8*8*16*64) return;
  int lane = idx & 63;
  int kc = (idx >> 6) & 15;
  int jw = idx >> 10;
  int tr = lane & 15, kg = lane >> 4;
  int grow = (tr&3)*256 + jw*4 + (tr>>2);
  int k0 = kc*32 + kg*8;
  half_t* d = dst + (size_t)idx*8;
#pragma unroll
  for (int jj=0;jj<8;jj++){
    int k = k0 + jj;
    float v = (k < 256) ? Wih[grow*256 + k] : Whh[grow*256 + (k - 256)];
    d[jj] = (half_t)v;
  }
}

// x -> [t][g 0..15][k8 0..7][b 0..15][8] fp16 ; b_global = g*16+b, k = k8*8+jj
__global__ void prep_x(const float* __restrict__ x, half_t* __restrict__ xblk){
  int idx = blockIdx.x*blockDim.x + threadIdx.x;
  if (idx >= 512*16*8*16) return;
  int b = idx & 15;
  int k8 = (idx >> 4) & 7;
  int g = (idx >> 7) & 15;
  int t = idx >> 11;
  const float* src = x + ((size_t)(g*16+b)*512 + (size_t)t)*64 + k8*8;
  half_t* d = xblk + (size_t)idx*8;
#pragma unroll
  for (int jj=0;jj<8;jj++) d[jj] = (half_t)src[jj];
}

// persistent distributed 2-layer LSTM: 16 groups x 8 WGs; WG owns 32 h x 16 batch
// exchange: per-value stamped u32 ((step+1)<<16 | fp16) -> poll IS the data, 1 RTT
// same-address slot-reuse safety: each phase's __syncthreads drains vmcnt(0)
__global__ __launch_bounds__(THREADS, 1) void lstm_dist(
    const half_t* __restrict__ W0blk, const half_t* __restrict__ W1blk,
    const half_t* __restrict__ xblk,
    u32* __restrict__ h0x, u32* __restrict__ h1x,
    const float* __restrict__ b_ih0, const float* __restrict__ b_hh0,
    const float* __restrict__ b_ih1, const float* __restrict__ b_hh1,
    const float* __restrict__ W_head, const float* __restrict__ b_head,
    float* __restrict__ out)
{
  __shared__ __align__(16) half_t hbuf[2][8192];  // [slot][h0:4096 | h1:4096] halves

  const int tid = threadIdx.x;
  const int wave = tid >> 6, lane = tid & 63;
  const int lcol = lane & 15, kg = lane >> 4;
  const int bid = blockIdx.x;
  const int g = bid >> 3, j = bid & 7;   // r8 mapping (cross-XCD groups; r9 local was slower)
  const int jw = j*8 + wave;

  // ---- one-time: A-fragments + biases into registers (512-VGPR budget now) ----
  half8 a0[10], a1[16];
#pragma unroll
  for (int kc = 0; kc < 10; ++kc)
    a0[kc] = *(const half8*)(W0blk + ((size_t)(jw*10 + kc)*64 + lane)*8);
#pragma unroll
  for (int kc = 0; kc < 16; ++kc)
    a1[kc] = *(const half8*)(W1blk + ((size_t)(jw*16 + kc)*64 + lane)*8);
#pragma unroll
  for (int kc = 0; kc < 10; ++kc) asm volatile("" : "+v"(a0[kc]));
#pragma unroll
  for (int kc = 0; kc < 16; ++kc) asm volatile("" : "+v"(a1[kc]));

  const int hh = jw*4 + kg;                              // lane's hidden index (0..255)
  const int eoff = ((hh>>3)*16 + lcol)*8 + (hh&7);       // exchange/LDS element index
  f32x4 bias0, bias1;
#pragma unroll
  for (int ri = 0; ri < 4; ++ri){
    bias0[ri] = b_ih0[ri*256+hh] + b_hh0[ri*256+hh];
    bias1[ri] = b_ih1[ri*256+hh] + b_hh1[ri*256+hh];
  }

  // zero both LDS slots (serves as h0(-1)=h1(-1)=h1(-2)=0)
  for (int i = tid; i < 8192; i += THREADS) ((u32*)hbuf)[i] = 0u;

  float c0 = 0.f, c1 = 0.f;
  half8 xf0, xf1;
  {
    const half_t* xs = xblk + (size_t)g*1024;
    xf0 = *(const half8*)(xs + ((0*4+kg)*16 + lcol)*8);
    xf1 = *(const half8*)(xs + ((1*4+kg)*16 + lcol)*8);
  }

  for (int q = 0; q <= TSTEPS; ++q){
    const int sslot = (q+1)&1, dslot = q&1;
    const u32 want = (u32)q;

    // ---- A) poll+stage h0(q-1): stamped payload poll (poll IS the fetch) ----
    if (q > 0){
      const u64* s0 = (const u64*)(h0x + (size_t)(sslot*GROUPS + g)*4096);
      u64 v[4];
      int ok = 0;
      for (int tries = 0; !ok && tries < (1<<20); ++tries){
        ok = 1;
#pragma unroll
        for (int i = 0; i < 4; ++i)
          v[i] = __hip_atomic_load(s0 + tid + i*512, __ATOMIC_RELAXED, __HIP_MEMORY_SCOPE_AGENT);
#pragma unroll
        for (int i = 0; i < 4; ++i)
          ok &= (int)((((u32)(v[i] >> 16) & 0xFFFFu) >= want) & (((u32)(v[i] >> 48)) >= want));
      }
      u32* lds0 = (u32*)hbuf[sslot];
#pragma unroll
      for (int i = 0; i < 4; ++i)
        lds0[tid + i*512] = ((u32)v[i] & 0xFFFFu) | (((u32)(v[i] >> 32) & 0xFFFFu) << 16);
    }
    __syncthreads();   // also drains (vmcnt 0) last phase's L1 stores -> slot-reuse safe

    const half_t* cb = hbuf[sslot];
    half8 h0f[8];
#pragma unroll
    for (int c = 0; c < 8; ++c)
      h0f[c] = *(const half8*)(cb + ((c*4+kg)*16 + lcol)*8);

    // ---- B) L0: step q ----
    if (q < TSTEPS){
      f32x4 acc = bias0;
      acc = __builtin_amdgcn_mfma_f32_16x16x32_f16(a0[0], xf0, acc, 0,0,0);
      acc = __builtin_amdgcn_mfma_f32_16x16x32_f16(a0[1], xf1, acc, 0,0,0);
#pragma unroll
      for (int c = 0; c < 8; ++c)
        acc = __builtin_amdgcn_mfma_f32_16x16x32_f16(a0[c+2], h0f[c], acc, 0,0,0);
      float ig=sigm(acc[0]), fg=sigm(acc[1]), gg=tanh_fast(acc[2]), og=sigm(acc[3]);
      c0 = fg*c0 + ig*gg;
      float hv = og*tanh_fast(c0);
      u32 sv = ((u32)(q+1) << 16) | (u32)__builtin_bit_cast(unsigned short, (half_t)hv);
      __hip_atomic_store(h0x + (size_t)(dslot*GROUPS + g)*4096 + eoff, sv,
                         __ATOMIC_RELAXED, __HIP_MEMORY_SCOPE_AGENT);
      __builtin_amdgcn_sched_barrier(0);   // issue the store before the h1 poll
    }

    // ---- C) poll+stage h1(q-2): overlaps producers' L1 of phase q-1 ----
    if (q > 1){
      const u64* s1 = (const u64*)(h1x + (size_t)(sslot*GROUPS + g)*4096);
      u64 v[4];
      int ok = 0;
      for (int tries = 0; !ok && tries < (1<<20); ++tries){
        ok = 1;
#pragma unroll
        for (int i = 0; i < 4; ++i)
          v[i] = __hip_atomic_load(s1 + tid + i*512, __ATOMIC_RELAXED, __HIP_MEMORY_SCOPE_AGENT);
#pragma unroll
        for (int i = 0; i < 4; ++i)
          ok &= (int)((((u32)(v[i] >> 16) & 0xFFFFu) >= want) & (((u32)(v[i] >> 48)) >= want));
      }
      u32* lds1 = (u32*)(hbuf[sslot] + 4096);
#pragma unroll
      for (int i = 0; i < 4; ++i)
        lds1[tid + i*512] = ((u32)v[i] & 0xFFFFu) | (((u32)(v[i] >> 32) & 0xFFFFu) << 16);
    }
    __syncthreads();   // drains this phase's L0 store too (overlapped with the poll)

    // ---- D) L1: step q-1 ----
    if (q >= 1){
      f32x4 acc = bias1;
#pragma unroll
      for (int c = 0; c < 8; ++c)
        acc = __builtin_amdgcn_mfma_f32_16x16x32_f16(a1[c], h0f[c], acc, 0,0,0);
#pragma unroll
      for (int c = 0; c < 8; ++c){
        half8 h1f = *(const half8*)(cb + 4096 + ((c*4+kg)*16 + lcol)*8);
        acc = __builtin_amdgcn_mfma_f32_16x16x32_f16(a1[c+8], h1f, acc, 0,0,0);
      }
      float ig=sigm(acc[0]), fg=sigm(acc[1]), gg=tanh_fast(acc[2]), og=sigm(acc[3]);
      c1 = fg*c1 + ig*gg;
      float hv = og*tanh_fast(c1);
      u32 sv = ((u32)(q+1) << 16) | (u32)__builtin_bit_cast(unsigned short, (half_t)hv);
      __hip_atomic_store(h1x + (size_t)(dslot*GROUPS + g)*4096 + eoff, sv,
                         __ATOMIC_RELAXED, __HIP_MEMORY_SCOPE_AGENT);
    }

    // ---- E) x prefetch (overlaps next phase's h0 poll) ----
    if (q+1 < TSTEPS){
      const half_t* xs = xblk + (size_t)((q+1)*16 + g)*1024;
      xf0 = *(const half8*)(xs + ((0*4+kg)*16 + lcol)*8);
      xf1 = *(const half8*)(xs + ((1*4+kg)*16 + lcol)*8);
    }
  }

  __syncthreads();

  // ---- head: poll final h1(511) (slot 0, stamp 513), stage, GEMV ----
  {
    const u64* s1 = (const u64*)(h1x + (size_t)(0*GROUPS + g)*4096);
    const u32 want = (u32)(TSTEPS + 1);
    u64 v[4];
    int ok = 0;
    for (int tries = 0; !ok && tries < (1<<20); ++tries){
      ok = 1;
#pragma unroll
      for (int i = 0; i < 4; ++i)
        v[i] = __hip_atomic_load(s1 + tid + i*512, __ATOMIC_RELAXED, __HIP_MEMORY_SCOPE_AGENT);
#pragma unroll
      for (int i = 0; i < 4; ++i)
        ok &= (int)((((u32)(v[i] >> 16) & 0xFFFFu) >= want) & (((u32)(v[i] >> 48)) >= want));
    }
    u32* hd = (u32*)hbuf[0];
#pragma unroll
    for (int i = 0; i < 4; ++i)
      hd[tid + i*512] = ((u32)v[i] & 0xFFFFu) | (((u32)(v[i] >> 32) & 0xFFFFu) << 16);
    __syncthreads();

    if (tid < 240){
      int bl = 2*j + (tid >= 120 ? 1 : 0);
      int o = tid % 120;
      float s2 = b_head[o];
      const float* wr = W_head + (size_t)o*256;
#pragma unroll 4
      for (int k8 = 0; k8 < 32; ++k8){
        half8 hv = *(const half8*)(hbuf[0] + (k8*16 + bl)*8);
#pragma unroll
        for (int jj = 0; jj < 8; ++jj)
          s2 += (float)hv[jj] * wr[k8*8 + jj];
      }
      out[((size_t)(g*16 + bl))*120 + o] = s2;
    }
  }
}

extern "C" void kernel_launch(void* const* d_in, const int* in_sizes, int n_in,
                              void* d_out, int out_size, void* d_ws, size_t ws_size,
                              hipStream_t stream){
  const float* x     = (const float*)d_in[0];
  const float* W_ih0 = (const float*)d_in[1];
  const float* W_hh0 = (const float*)d_in[2];
  const float* b_ih0 = (const float*)d_in[3];
  const float* b_hh0 = (const float*)d_in[4];
  const float* W_ih1 = (const float*)d_in[5];
  const float* W_hh1 = (const float*)d_in[6];
  const float* b_ih1 = (const float*)d_in[7];
  const float* b_hh1 = (const float*)d_in[8];
  const float* W_head= (const float*)d_in[9];
  const float* b_head= (const float*)d_in[10];
  float* out = (float*)d_out;

  half_t* W0blk = (half_t*)d_ws;
  half_t* W1blk = W0blk + W0_HALVES;
  half_t* xblk  = W1blk + W1_HALVES;
  u32*    h0x   = (u32*)(xblk + X_HALVES);
  u32*    h1x   = h0x + HX_U32;

  // zero stamped exchange buffers every launch (graph-replay safe)
  (void)hipMemsetAsync(h0x, 0, (size_t)HX_U32*2*4, stream);   // h0x + h1x contiguous

  hipLaunchKernelGGL(prep_w0, dim3(160), dim3(256), 0, stream, W_ih0, W_hh0, W0blk);
  hipLaunchKernelGGL(prep_w1, dim3(256), dim3(256), 0, stream, W_ih1, W_hh1, W1blk);
  hipLaunchKernelGGL(prep_x,  dim3(4096), dim3(256), 0, stream, x, xblk);

  hipLaunchKernelGGL(lstm_dist, dim3(NWG), dim3(THREADS), 0, stream,
                     W0blk, W1blk, xblk, h0x, h1x,
                     b_ih0, b_hh0, b_ih1, b_hh1, W_head, b_head, out);
}